// Round 2
// baseline (247.083 us; speedup 1.0000x reference)
//
#include <hip/hip_runtime.h>

// AtomEncoderLayer: B=4, N=32, D=128, H=8, NC=27, DK=16, DFF=512, L=864.
// All float tensors are fp32 (per the reference dtypes); mask is int32.
// Strategy: LayerNorm affine decomposition. a^(i) = u - P_i with
// u = x + bp + coords@Wp, P = coords@Wp. Then
//   LN(a^(i)) = (uhat - phat_i) * inv_std * g1 + b1,
//   inv_std(n,i) = rsqrt(var_u[n] + var_p[i] - 2*cov(uhat_n, phat_i) + eps)
// so K/V become inv_std*(Ak - Ck_i) + ek with Ak/Ck computed ONCE (not per i).

#define B_ 4
#define N_ 32
#define D_ 128
#define H_ 8
#define NC_ 27
#define DFF_ 512
#define L_ (NC_*N_)        // 864
#define ROWS_ (B_*NC_*N_)  // 3456

// butterfly sum within each 16-lane segment (heads); masks <16 never cross
__device__ __forceinline__ float red16(float v){
  v += __shfl_xor(v, 1);
  v += __shfl_xor(v, 2);
  v += __shfl_xor(v, 4);
  v += __shfl_xor(v, 8);
  return v;
}

// dual block-wide (exactly 128 threads = 2 waves) sum reduction
__device__ __forceinline__ void red2_block128(float& a, float& b, float* sbuf, int tid){
  for (int off = 32; off; off >>= 1){ a += __shfl_xor(a, off); b += __shfl_xor(b, off); }
  if ((tid & 63) == 0){ sbuf[(tid>>6)*2+0] = a; sbuf[(tid>>6)*2+1] = b; }
  __syncthreads();
  a = sbuf[0] + sbuf[2];
  b = sbuf[1] + sbuf[3];
  __syncthreads();   // safe reuse of sbuf
}

// K1: per row (b,c,n): P = coords@Wp, u = x + bp + P; store centered uhat/phat + vars
__global__ void k_prep(const float* __restrict__ x, const float* __restrict__ coords,
                       const float* __restrict__ Wp, const float* __restrict__ bp,
                       float* __restrict__ uhat, float* __restrict__ phat,
                       float* __restrict__ var_u, float* __restrict__ var_p){
  __shared__ float sbuf[4];
  int row = blockIdx.x;              // (b*NC+c)*N+n
  int tid = threadIdx.x;             // 0..127
  int b = row / (NC_*N_);
  int n = row % N_;
  float c0 = coords[row*3+0];
  float c1 = coords[row*3+1];
  float c2 = coords[row*3+2];
  float p = c0*Wp[0*D_+tid] + c1*Wp[1*D_+tid] + c2*Wp[2*D_+tid];
  float u = x[(b*N_+n)*D_+tid] + bp[tid] + p;
  float su = u, sp = p;
  red2_block128(su, sp, sbuf, tid);
  float uh = u - su*(1.f/D_);
  float ph = p - sp*(1.f/D_);
  float vu = uh*uh, vp = ph*ph;
  red2_block128(vu, vp, sbuf, tid);
  uhat[row*D_+tid] = uh;
  phat[row*D_+tid] = ph;
  if (tid == 0){ var_u[row] = vu*(1.f/D_); var_p[row] = vp*(1.f/D_); }
}

// K2: Ak = (uhat*g1)@Wk, Av = (uhat*g1)@Wv, Ck = (phat*g1)@Wk, Cv = (phat*g1)@Wv
__global__ void k_proj(const float* __restrict__ uhat, const float* __restrict__ phat,
                       const float* __restrict__ g1,
                       const float* __restrict__ Wk, const float* __restrict__ Wv,
                       float* __restrict__ Ak, float* __restrict__ Av,
                       float* __restrict__ Ck, float* __restrict__ Cv){
  __shared__ float ug[D_], pg[D_];
  int row = blockIdx.x, tid = threadIdx.x;
  float g = g1[tid];
  ug[tid] = uhat[row*D_+tid]*g;
  pg[tid] = phat[row*D_+tid]*g;
  __syncthreads();
  float ak=0.f, av=0.f, ck=0.f, cv=0.f;
  #pragma unroll 8
  for (int e=0;e<D_;e++){
    float wk = Wk[e*D_+tid];
    float wv = Wv[e*D_+tid];
    float ue = ug[e], pe = pg[e];
    ak += ue*wk; av += ue*wv;
    ck += pe*wk; cv += pe*wv;
  }
  Ak[row*D_+tid]=ak; Av[row*D_+tid]=av; Ck[row*D_+tid]=ck; Cv[row*D_+tid]=cv;
}

// K3: gram cov(uhat_n, phat_i) per (b,c); inv_std stored [b][i][c][n] for coalesced attn read
__global__ void k_cov(const float* __restrict__ uhat, const float* __restrict__ phat,
                      const float* __restrict__ var_u, const float* __restrict__ var_p,
                      float* __restrict__ inv_std){
  __shared__ float ut[N_][D_+2], pt[N_][D_+2];   // +2 pad: stride 130 -> 2-way bank alias (free)
  __shared__ float vu_s[N_], vp_s[N_];
  int bc = blockIdx.x, tid = threadIdx.x;        // 256 threads
  int row0 = bc*N_;
  int b = bc / NC_, c = bc % NC_;
  for (int idx = tid; idx < N_*D_; idx += 256){
    int n = idx >> 7, d2 = idx & 127;
    ut[n][d2] = uhat[(row0+n)*D_ + d2];
    pt[n][d2] = phat[(row0+n)*D_ + d2];
  }
  if (tid < N_){ vu_s[tid] = var_u[row0+tid]; vp_s[tid] = var_p[row0+tid]; }
  __syncthreads();
  for (int pair = tid; pair < N_*N_; pair += 256){
    int n = pair >> 5, i = pair & 31;
    float dot = 0.f;
    #pragma unroll 8
    for (int d2=0; d2<D_; d2++) dot += ut[n][d2]*pt[i][d2];
    inv_std[((b*N_+i)*NC_+c)*N_ + n] =
        rsqrtf(fmaxf(vu_s[n] + vp_s[i] - 2.f*dot*(1.f/D_), 0.f) + 1e-5f);
  }
}

// K4: q row for each (b,i): LN(x[b,i]+bp) @ Wq + bq   (kept row l=i is image 0, atom i: a = x+bp)
__global__ void k_qrow(const float* __restrict__ x, const float* __restrict__ bp,
                       const float* __restrict__ g1, const float* __restrict__ b1,
                       const float* __restrict__ Wq, const float* __restrict__ bq,
                       float* __restrict__ qbuf){
  __shared__ float sbuf[4];
  __shared__ float hn_s[D_];
  int row = blockIdx.x, tid = threadIdx.x;   // row = b*N+i
  float t = x[row*D_+tid] + bp[tid];
  float s1 = t, dm = 0.f;
  red2_block128(s1, dm, sbuf, tid);
  float dev = t - s1*(1.f/D_);
  float v1 = dev*dev; dm = 0.f;
  red2_block128(v1, dm, sbuf, tid);
  float hn = dev*rsqrtf(v1*(1.f/D_) + 1e-5f)*g1[tid] + b1[tid];
  hn_s[tid] = hn;
  __syncthreads();
  float acc = bq[tid];
  #pragma unroll 8
  for (int e=0;e<D_;e++) acc += hn_s[e]*Wq[e*D_+tid];
  qbuf[row*D_+tid] = acc;
}

// K4b: ek = b1@Wk + bk, ev = b1@Wv + bv
__global__ void k_consts(const float* __restrict__ b1, const float* __restrict__ Wk,
                         const float* __restrict__ bk, const float* __restrict__ Wv,
                         const float* __restrict__ bv, float* __restrict__ ekv){
  __shared__ float b1s[D_];
  int tid = threadIdx.x;
  b1s[tid] = b1[tid];
  __syncthreads();
  float ek = bk[tid], ev = bv[tid];
  for (int e=0;e<D_;e++){ float be = b1s[e]; ek += be*Wk[e*D_+tid]; ev += be*Wv[e*D_+tid]; }
  ekv[tid] = ek; ekv[D_+tid] = ev;
}

// K5: fused attention per (b,i). 512 threads = 4 key-groups x 128 (one lane per dim d).
// score(l) = 0.25*(is(l)*(q.Ak_l - q.Ck_i) + q.ek), online softmax per head,
// att_d = (sum e*is*Av - sum_c T_c*Cv_c)/s + ev, then row @ Wo + residual.
__global__ __launch_bounds__(512) void k_attn(
    const float* __restrict__ Ak, const float* __restrict__ Av,
    const float* __restrict__ Ck, const float* __restrict__ Cv,
    const float* __restrict__ inv_std, const float* __restrict__ qbuf,
    const float* __restrict__ ekv, const int* __restrict__ mask,
    const float* __restrict__ x, const float* __restrict__ bp,
    const float* __restrict__ Wo, const float* __restrict__ bo,
    float* __restrict__ ybuf){
  __shared__ float is_s[L_];
  __shared__ int   mask_s[N_];
  __shared__ float S2_s[H_*NC_];
  __shared__ float m_s[4][H_], s_s[4][H_];
  __shared__ float acc_s[4][D_];
  __shared__ float T_s[4][H_][NC_];
  __shared__ float att_s[D_];
  int bi = blockIdx.x;             // b*32+i
  int b = bi >> 5, i = bi & 31;
  int tid = threadIdx.x;
  int g = tid >> 7, d = tid & 127;
  int h = d >> 4, dk = d & 15;
  const float* isp = inv_std + (size_t)bi*L_;
  for (int idx = tid; idx < L_; idx += 512) is_s[idx] = isp[idx];
  if (tid < N_) mask_s[tid] = mask[b*N_+tid];
  float qd = qbuf[bi*D_ + d];
  float S3 = red16(qd * ekv[d]);
  float evd = ekv[D_ + d];
  if (g == 0){                      // waves 0,1 compute S2[h][c] = q . Ck(b,c,i)
    for (int c=0;c<NC_;c++){
      float S2 = red16(qd * Ck[(size_t)((b*NC_+c)*N_+i)*D_ + d]);
      if (dk == 0) S2_s[h*NC_+c] = S2;
    }
  }
  __syncthreads();
  float m = -3.0e38f, s = 0.f, acc = 0.f, T0 = 0.f, T1 = 0.f;
  for (int j=0;j<L_/4;j++){
    int l = j*4 + g;
    int c = l >> 5, n = l & 31;
    size_t roff = (size_t)((b*NC_+c)*N_+n)*D_ + d;
    float akd = Ak[roff], avd = Av[roff];
    float S1 = red16(qd*akd);
    float isd = is_s[l];
    float sc = 0.25f*(isd*(S1 - S2_s[h*NC_+c]) + S3);
    sc = mask_s[n] ? sc : -1e9f;
    float mnew = fmaxf(m, sc);
    float scale = expf(m - mnew);   // first iter: exp(-3e38)=0
    float w = expf(sc - mnew);
    s = s*scale + w;
    float t = w*isd;
    acc = acc*scale + t*avd;
    T0 = T0*scale + ((c == dk)      ? t : 0.f);
    T1 = T1*scale + ((c == dk + 16) ? t : 0.f);
    m = mnew;
  }
  if (dk == 0){ m_s[g][h] = m; s_s[g][h] = s; }
  acc_s[g][d] = acc;
  T_s[g][h][dk] = T0;
  if (dk < NC_ - 16) T_s[g][h][dk+16] = T1;
  __syncthreads();
  if (g == 0){
    float M = fmaxf(fmaxf(m_s[0][h], m_s[1][h]), fmaxf(m_s[2][h], m_s[3][h]));
    float e0 = expf(m_s[0][h]-M), e1 = expf(m_s[1][h]-M);
    float e2 = expf(m_s[2][h]-M), e3 = expf(m_s[3][h]-M);
    float S = s_s[0][h]*e0 + s_s[1][h]*e1 + s_s[2][h]*e2 + s_s[3][h]*e3;
    S = fmaxf(S, 1e-30f);
    float A = acc_s[0][d]*e0 + acc_s[1][d]*e1 + acc_s[2][d]*e2 + acc_s[3][d]*e3;
    float corr = 0.f;
    for (int c=0;c<NC_;c++){
      float Tc = T_s[0][h][c]*e0 + T_s[1][h][c]*e1 + T_s[2][h][c]*e2 + T_s[3][h][c]*e3;
      corr += Tc * Cv[(size_t)((b*NC_+c)*N_+i)*D_ + d];
    }
    att_s[d] = (A - corr)/S + evd;
  }
  __syncthreads();
  if (g == 0){
    float o = x[bi*D_+d] + bp[d] + bo[d];
    #pragma unroll 8
    for (int e=0;e<D_;e++) o += att_s[e]*Wo[e*D_+d];
    ybuf[bi*D_+d] = o;
  }
}

// K6: out = y + relu(LN(y;g2,b2)@W1 + bf1)@W2 + bf2
__global__ void k_ffn(const float* __restrict__ ybuf,
                      const float* __restrict__ g2, const float* __restrict__ b2,
                      const float* __restrict__ W1, const float* __restrict__ bf1,
                      const float* __restrict__ W2, const float* __restrict__ bfb2,
                      float* __restrict__ out){
  __shared__ float sbuf[4];
  __shared__ float hn_s[D_];
  __shared__ float f_s[DFF_];
  int row = blockIdx.x, tid = threadIdx.x;
  float yv = ybuf[row*D_+tid];
  float s1 = yv, dm = 0.f;
  red2_block128(s1, dm, sbuf, tid);
  float dev = yv - s1*(1.f/D_);
  float v1 = dev*dev; dm = 0.f;
  red2_block128(v1, dm, sbuf, tid);
  float hn = dev*rsqrtf(v1*(1.f/D_)+1e-5f)*g2[tid] + b2[tid];
  hn_s[tid] = hn;
  __syncthreads();
  float f0=0.f,f1=0.f,f2=0.f,f3=0.f;
  #pragma unroll 4
  for (int e=0;e<D_;e++){
    float he = hn_s[e];
    const float* wr = W1 + e*DFF_ + tid;
    f0 += he*wr[0];   f1 += he*wr[128];
    f2 += he*wr[256]; f3 += he*wr[384];
  }
  f_s[tid]     = fmaxf(f0 + bf1[tid],     0.f);
  f_s[tid+128] = fmaxf(f1 + bf1[tid+128], 0.f);
  f_s[tid+256] = fmaxf(f2 + bf1[tid+256], 0.f);
  f_s[tid+384] = fmaxf(f3 + bf1[tid+384], 0.f);
  __syncthreads();
  float o = yv + bfb2[tid];
  #pragma unroll 8
  for (int j=0;j<DFF_;j++) o += f_s[j]*W2[j*D_+tid];
  out[row*D_+tid] = o;
}

extern "C" void kernel_launch(void* const* d_in, const int* in_sizes, int n_in,
                              void* d_out, int out_size, void* d_ws, size_t ws_size,
                              hipStream_t stream){
  const float* x      = (const float*)d_in[0];
  const int*   mask   = (const int*)  d_in[1];
  const float* coords = (const float*)d_in[2];
  const float* Wp     = (const float*)d_in[3];
  const float* bp     = (const float*)d_in[4];
  const float* Wq     = (const float*)d_in[5];
  const float* bq     = (const float*)d_in[6];
  const float* Wk     = (const float*)d_in[7];
  const float* bk     = (const float*)d_in[8];
  const float* Wv     = (const float*)d_in[9];
  const float* bv     = (const float*)d_in[10];
  const float* Wo     = (const float*)d_in[11];
  const float* bo     = (const float*)d_in[12];
  const float* g1     = (const float*)d_in[13];
  const float* b1     = (const float*)d_in[14];
  const float* g2     = (const float*)d_in[15];
  const float* b2     = (const float*)d_in[16];
  const float* W1     = (const float*)d_in[17];
  const float* bf1    = (const float*)d_in[18];
  const float* W2     = (const float*)d_in[19];
  const float* bfb2   = (const float*)d_in[20];

  // ws layout (fp32), total ~11.2 MB
  float* ws      = (float*)d_ws;
  float* uhat    = ws;
  float* phat    = uhat    + (size_t)ROWS_*D_;
  float* Akb     = phat    + (size_t)ROWS_*D_;
  float* Avb     = Akb     + (size_t)ROWS_*D_;
  float* Ckb     = Avb     + (size_t)ROWS_*D_;
  float* Cvb     = Ckb     + (size_t)ROWS_*D_;
  float* var_u   = Cvb     + (size_t)ROWS_*D_;
  float* var_p   = var_u   + ROWS_;
  float* inv_std = var_p   + ROWS_;
  float* qbuf    = inv_std + (size_t)B_*N_*L_;
  float* ekv     = qbuf    + B_*N_*D_;
  float* ybuf    = ekv     + 2*D_;

  k_prep  <<<ROWS_,   D_,  0, stream>>>(x, coords, Wp, bp, uhat, phat, var_u, var_p);
  k_proj  <<<ROWS_,   D_,  0, stream>>>(uhat, phat, g1, Wk, Wv, Akb, Avb, Ckb, Cvb);
  k_cov   <<<B_*NC_,  256, 0, stream>>>(uhat, phat, var_u, var_p, inv_std);
  k_qrow  <<<B_*N_,   D_,  0, stream>>>(x, bp, g1, b1, Wq, bq, qbuf);
  k_consts<<<1,       D_,  0, stream>>>(b1, Wk, bk, Wv, bv, ekv);
  k_attn  <<<B_*N_,   512, 0, stream>>>(Akb, Avb, Ckb, Cvb, inv_std, qbuf, ekv,
                                        mask, x, bp, Wo, bo, ybuf);
  k_ffn   <<<B_*N_,   D_,  0, stream>>>(ybuf, g2, b2, W1, bf1, W2, bfb2, (float*)d_out);
}

// Round 3
// 152.681 us; speedup vs baseline: 1.6183x; 1.6183x over previous
//
#include <hip/hip_runtime.h>

// AtomEncoderLayer: B=4, N=32, D=128, H=8, NC=27, DK=16, DFF=512, L=864.
// fp32 tensors, int32 mask. LayerNorm affine decomposition:
//   a^(i) = u - P_i, u = x + bp + coords@Wp, P = coords@Wp
//   LN(a^(i)) = (uhat - phat_i)*inv_std*g1 + b1
//   inv_std(n,i) = rsqrt(var_u[n]+var_p[i]-2*cov(uhat_n,phat_i)+eps)
// K/V = inv_std*(Ak - Ck_i) + ek with Ak/Ck computed once.
// 3 kernels: k_mid (prep+proj / prep+cov / qrow / consts by blockIdx),
// k_attp (attention partials per (b,i,c) chunk), k_tail (merge+Wo+LN+FFN).

#define B_ 4
#define N_ 32
#define D_ 128
#define H_ 8
#define NC_ 27
#define DFF_ 512
#define L_ (NC_*N_)        // 864
#define ROWS_ (B_*NC_*N_)  // 3456

__device__ __forceinline__ float red16(float v){
  v += __shfl_xor(v, 1);
  v += __shfl_xor(v, 2);
  v += __shfl_xor(v, 4);
  v += __shfl_xor(v, 8);
  return v;
}

// dual-value sum over each 128-thread group (block = 512 thr = 4 groups).
// Double-buffered by phase parity: exactly one __syncthreads per call.
__device__ __forceinline__ void gred2(float& a, float& b, float sred[2][8][2],
                                      int tid, int phase){
  for (int off = 32; off; off >>= 1){ a += __shfl_xor(a, off); b += __shfl_xor(b, off); }
  int pb = phase & 1;
  if ((tid & 63) == 0){ sred[pb][tid>>6][0] = a; sred[pb][tid>>6][1] = b; }
  __syncthreads();
  int w0 = (tid >> 7) << 1;
  a = sred[pb][w0][0] + sred[pb][w0+1][0];
  b = sred[pb][w0][1] + sred[pb][w0+1][1];
}

// dual-value sum over the whole 512-thread block (callers zero inactive lanes)
__device__ __forceinline__ void bred2(float& a, float& b, float sred[2][8][2],
                                      int tid, int phase){
  for (int off = 32; off; off >>= 1){ a += __shfl_xor(a, off); b += __shfl_xor(b, off); }
  int pb = phase & 1;
  if ((tid & 63) == 0){ sred[pb][tid>>6][0] = a; sred[pb][tid>>6][1] = b; }
  __syncthreads();
  float sa = 0.f, sb = 0.f;
  #pragma unroll
  for (int w = 0; w < 8; w++){ sa += sred[pb][w][0]; sb += sred[pb][w][1]; }
  a = sa; b = sb;
}

// K1 multi-role kernel, 512 threads.
// blocks [0,864): prep+proj, 4 rows/block (Ak/Av/Ck/Cv)
// blocks [864,972): prep(recompute)+cov -> inv_std
// blocks [972,1100): q rows
// block 1100: ek/ev constants
__global__ __launch_bounds__(512) void k_mid(
    const float* __restrict__ x, const float* __restrict__ coords,
    const float* __restrict__ Wp, const float* __restrict__ bp,
    const float* __restrict__ g1, const float* __restrict__ b1,
    const float* __restrict__ Wq, const float* __restrict__ bq,
    const float* __restrict__ Wk, const float* __restrict__ bk,
    const float* __restrict__ Wv, const float* __restrict__ bv,
    float* __restrict__ Ak, float* __restrict__ Av,
    float* __restrict__ Ck, float* __restrict__ Cv,
    float* __restrict__ inv_std, float* __restrict__ qbuf,
    float* __restrict__ ekv){
  __shared__ float smem[2*32*132 + 64];   // cov footprint is the max (~34 KB)
  __shared__ float sred[2][8][2];
  int blk = blockIdx.x, tid = threadIdx.x;
  int slot = tid >> 7, d = tid & 127;

  if (blk < 864){
    // ---- prep + proj, rows blk*4 .. blk*4+3 ----
    float* ug = smem;            // [4][128] uhat*g1
    float* pg = smem + 512;      // [4][128] phat*g1
    int row = blk*4 + slot;                 // (b*NC+c)*N+n
    int b = row / (NC_*N_);
    int n = row & (N_-1);
    float c0 = coords[row*3+0], c1 = coords[row*3+1], c2 = coords[row*3+2];
    float p = c0*Wp[d] + c1*Wp[D_+d] + c2*Wp[2*D_+d];
    float u = x[(b*N_+n)*D_+d] + bp[d] + p;
    float su = u, sp = p;
    gred2(su, sp, sred, tid, 0);
    float g = g1[d];
    ug[slot*D_+d] = (u - su*(1.f/D_))*g;
    pg[slot*D_+d] = (p - sp*(1.f/D_))*g;
    __syncthreads();
    float ak=0.f, av=0.f, ck=0.f, cv=0.f;
    #pragma unroll 8
    for (int e=0;e<D_;e++){
      float wk = Wk[e*D_+d], wv = Wv[e*D_+d];
      float ue = ug[slot*D_+e], pe = pg[slot*D_+e];
      ak += ue*wk; av += ue*wv;
      ck += pe*wk; cv += pe*wv;
    }
    size_t o = (size_t)row*D_ + d;
    Ak[o]=ak; Av[o]=av; Ck[o]=ck; Cv[o]=cv;
  } else if (blk < 972){
    // ---- prep(recompute) + cov for one (b,c) ----
    int bc = blk - 864;
    int b = bc / NC_, c = bc % NC_;
    float* ut   = smem;                 // [32][132]
    float* pt   = smem + 32*132;        // [32][132]
    float* vu_s = smem + 2*32*132;      // [32]
    float* vp_s = vu_s + 32;            // [32]
    int phase = 0;
    for (int it=0; it<8; it++){
      int r = it*4 + slot;
      int row = bc*N_ + r;
      float c0 = coords[row*3+0], c1 = coords[row*3+1], c2 = coords[row*3+2];
      float p = c0*Wp[d] + c1*Wp[D_+d] + c2*Wp[2*D_+d];
      float u = x[(b*N_+r)*D_+d] + bp[d] + p;
      float su = u, sp = p;
      gred2(su, sp, sred, tid, phase++);
      float uh = u - su*(1.f/D_), ph = p - sp*(1.f/D_);
      float vu = uh*uh, vp = ph*ph;
      gred2(vu, vp, sred, tid, phase++);
      ut[r*132+d] = uh; pt[r*132+d] = ph;
      if (d == 0){ vu_s[r] = vu*(1.f/D_); vp_s[r] = vp*(1.f/D_); }
    }
    __syncthreads();
    for (int rep=0; rep<2; rep++){
      int pair = tid + rep*512;
      int n = pair >> 5, i = pair & 31;
      const float4* un = (const float4*)(ut + n*132);
      const float4* pi = (const float4*)(pt + i*132);
      float dot = 0.f;
      #pragma unroll 8
      for (int j=0;j<32;j++){
        float4 a4 = un[j], b4 = pi[j];
        dot += a4.x*b4.x + a4.y*b4.y + a4.z*b4.z + a4.w*b4.w;
      }
      inv_std[((b*N_+i)*NC_+c)*N_ + n] =
          rsqrtf(fmaxf(vu_s[n] + vp_s[i] - 2.f*dot*(1.f/D_), 0.f) + 1e-5f);
    }
  } else if (blk < 1100){
    // ---- q row: LN(x+bp)@Wq + bq ----
    int row = blk - 972;                // b*N+i
    float* hn_s = smem;                 // [128]
    float* po   = smem + 128;           // [4][128]
    float t = (tid < D_) ? (x[row*D_+tid] + bp[tid]) : 0.f;
    float s1 = t, dm = 0.f;
    bred2(s1, dm, sred, tid, 0);
    float dev = t - s1*(1.f/D_);
    float v1 = (tid < D_) ? dev*dev : 0.f; dm = 0.f;
    bred2(v1, dm, sred, tid, 1);
    if (tid < D_) hn_s[tid] = dev*rsqrtf(v1*(1.f/D_)+1e-5f)*g1[tid] + b1[tid];
    __syncthreads();
    float acc = 0.f;
    for (int e=slot*32; e<slot*32+32; e++) acc += hn_s[e]*Wq[e*D_+d];
    po[slot*D_+d] = acc;
    __syncthreads();
    if (tid < D_)
      qbuf[row*D_+tid] = bq[tid] + po[tid] + po[D_+tid] + po[2*D_+tid] + po[3*D_+tid];
  } else {
    // ---- ek = b1@Wk+bk, ev = b1@Wv+bv ----
    float* b1s = smem;                  // [128]
    float* po  = smem + 128;            // [2][4][128]
    if (tid < D_) b1s[tid] = b1[tid];
    __syncthreads();
    float ek = 0.f, ev = 0.f;
    for (int e=slot*32; e<slot*32+32; e++){
      float be = b1s[e];
      ek += be*Wk[e*D_+d]; ev += be*Wv[e*D_+d];
    }
    po[slot*D_+d] = ek; po[512+slot*D_+d] = ev;
    __syncthreads();
    if (tid < D_){
      ekv[tid]    = bk[tid] + po[tid]+po[D_+tid]+po[2*D_+tid]+po[3*D_+tid];
      ekv[D_+tid] = bv[tid] + po[512+tid]+po[512+D_+tid]+po[512+2*D_+tid]+po[512+3*D_+tid];
    }
  }
}

// K2: attention partial per (b,i,c): 32 keys, 256 thr = 2 groups x 128 lanes.
// Writes pacc_d = acc_d - T_h*Cv[c,i,d] and (m_h, s_h).
__global__ __launch_bounds__(256) void k_attp(
    const float* __restrict__ Ak, const float* __restrict__ Av,
    const float* __restrict__ Ck, const float* __restrict__ Cv,
    const float* __restrict__ inv_std, const float* __restrict__ qbuf,
    const float* __restrict__ ekv, const int* __restrict__ mask,
    float* __restrict__ part_ms, float* __restrict__ part_pacc){
  __shared__ float is_s[N_];
  __shared__ int   mask_s[N_];
  __shared__ float m_l[2][H_], s_l[2][H_], T_l[2][H_];
  __shared__ float acc_l[2][D_];
  int blk = blockIdx.x;              // (b*N+i)*NC + c
  int bi = blk / NC_, c = blk % NC_;
  int b = bi >> 5, i = bi & (N_-1);
  int tid = threadIdx.x;
  int g = tid >> 7, d = tid & 127, h = d >> 4;
  if (tid < N_){
    is_s[tid]   = inv_std[(size_t)blk*N_ + tid];
    mask_s[tid] = mask[b*N_ + tid];
  }
  float qd = qbuf[bi*D_ + d];
  float S3 = red16(qd * ekv[d]);
  float S2 = red16(qd * Ck[(size_t)((b*NC_+c)*N_+i)*D_ + d]);
  __syncthreads();
  float m = -3.0e38f, s = 0.f, acc = 0.f, T = 0.f;
  for (int j=0;j<16;j++){
    int n = j*2 + g;
    size_t roff = (size_t)((b*NC_+c)*N_+n)*D_ + d;
    float akd = Ak[roff], avd = Av[roff];
    float S1 = red16(qd*akd);
    float isd = is_s[n];
    float sc = 0.25f*(isd*(S1 - S2) + S3);
    sc = mask_s[n] ? sc : -1e9f;
    float mnew = fmaxf(m, sc);
    float scale = expf(m - mnew);   // first iter: exp(-3e38)=0
    float w = expf(sc - mnew);
    s = s*scale + w;
    float t = w*isd;
    acc = acc*scale + t*avd;
    T = T*scale + t;
    m = mnew;
  }
  if ((d & 15) == 0){ m_l[g][h] = m; s_l[g][h] = s; T_l[g][h] = T; }
  acc_l[g][d] = acc;
  __syncthreads();
  if (g == 0){
    float m0 = m_l[0][h], m1 = m_l[1][h];
    float M = fmaxf(m0, m1);
    float e0 = expf(m0-M), e1 = expf(m1-M);
    float A  = acc_l[0][d]*e0 + acc_l[1][d]*e1;
    float Tm = T_l[0][h]*e0 + T_l[1][h]*e1;
    part_pacc[(size_t)blk*D_ + d] = A - Tm * Cv[(size_t)((b*NC_+c)*N_+i)*D_ + d];
    if (d < 16){
      int hh = d & 7;
      float mm0 = m_l[0][hh], mm1 = m_l[1][hh];
      float MM = fmaxf(mm0, mm1);
      float val = (d < 8) ? MM
                : (s_l[0][hh]*expf(mm0-MM) + s_l[1][hh]*expf(mm1-MM));
      part_ms[(size_t)blk*16 + d] = val;
    }
  }
}

// K3: per (b,i): merge 27 partials -> att; y = x+bp+att@Wo+bo; out = y + FFN(LN(y))
__global__ __launch_bounds__(512) void k_tail(
    const float* __restrict__ part_ms, const float* __restrict__ part_pacc,
    const float* __restrict__ ekv,
    const float* __restrict__ x, const float* __restrict__ bp,
    const float* __restrict__ Wo, const float* __restrict__ bo,
    const float* __restrict__ g2, const float* __restrict__ b2,
    const float* __restrict__ W1, const float* __restrict__ bf1,
    const float* __restrict__ W2, const float* __restrict__ bfb2,
    float* __restrict__ out){
  __shared__ float ms_s[NC_*16];
  __shared__ float att_s[D_];
  __shared__ float y_s[D_];
  __shared__ float hn_s[D_];
  __shared__ float f_s[DFF_];
  __shared__ float po[4][D_];
  __shared__ float sred[2][8][2];
  int bi = blockIdx.x, tid = threadIdx.x;
  int g = tid >> 7, d = tid & 127;
  if (tid < NC_*16) ms_s[tid] = part_ms[(size_t)bi*NC_*16 + tid];
  __syncthreads();
  if (tid < D_){
    int h = d >> 4;
    float M = -3.0e38f;
    for (int c=0;c<NC_;c++) M = fmaxf(M, ms_s[c*16+h]);
    float A = 0.f, S = 0.f;
    for (int c=0;c<NC_;c++){
      float e = expf(ms_s[c*16+h] - M);
      A += part_pacc[((size_t)bi*NC_+c)*D_ + d]*e;
      S += ms_s[c*16+8+h]*e;
    }
    att_s[d] = A/fmaxf(S, 1e-30f) + ekv[D_+d];
  }
  __syncthreads();
  {
    float a = 0.f;
    for (int e=g*32; e<g*32+32; e++) a += att_s[e]*Wo[e*D_+d];
    po[g][d] = a;
  }
  __syncthreads();
  float yv = 0.f;
  if (tid < D_){
    yv = x[bi*D_+tid] + bp[tid] + bo[tid] + po[0][tid]+po[1][tid]+po[2][tid]+po[3][tid];
    y_s[tid] = yv;
  }
  float s1 = (tid < D_) ? yv : 0.f, dm = 0.f;
  bred2(s1, dm, sred, tid, 0);          // also fences po reads before reuse
  float dev = yv - s1*(1.f/D_);
  float v1 = (tid < D_) ? dev*dev : 0.f; dm = 0.f;
  bred2(v1, dm, sred, tid, 1);
  if (tid < D_) hn_s[tid] = dev*rsqrtf(v1*(1.f/D_)+1e-5f)*g2[tid] + b2[tid];
  __syncthreads();
  float f = bf1[tid];
  #pragma unroll 8
  for (int e=0;e<D_;e++) f += hn_s[e]*W1[e*DFF_+tid];
  f_s[tid] = fmaxf(f, 0.f);
  __syncthreads();
  {
    float a = 0.f;
    #pragma unroll 8
    for (int j=g*128; j<g*128+128; j++) a += f_s[j]*W2[j*D_+d];
    po[g][d] = a;
  }
  __syncthreads();
  if (tid < D_)
    out[bi*D_+tid] = y_s[tid] + bfb2[tid] + po[0][tid]+po[1][tid]+po[2][tid]+po[3][tid];
}

extern "C" void kernel_launch(void* const* d_in, const int* in_sizes, int n_in,
                              void* d_out, int out_size, void* d_ws, size_t ws_size,
                              hipStream_t stream){
  const float* x      = (const float*)d_in[0];
  const int*   mask   = (const int*)  d_in[1];
  const float* coords = (const float*)d_in[2];
  const float* Wp     = (const float*)d_in[3];
  const float* bp     = (const float*)d_in[4];
  const float* Wq     = (const float*)d_in[5];
  const float* bq     = (const float*)d_in[6];
  const float* Wk     = (const float*)d_in[7];
  const float* bk     = (const float*)d_in[8];
  const float* Wv     = (const float*)d_in[9];
  const float* bv     = (const float*)d_in[10];
  const float* Wo     = (const float*)d_in[11];
  const float* bo     = (const float*)d_in[12];
  const float* g1     = (const float*)d_in[13];
  const float* b1     = (const float*)d_in[14];
  const float* g2     = (const float*)d_in[15];
  const float* b2     = (const float*)d_in[16];
  const float* W1     = (const float*)d_in[17];
  const float* bf1    = (const float*)d_in[18];
  const float* W2     = (const float*)d_in[19];
  const float* bfb2   = (const float*)d_in[20];

  // ws layout (fp32), ~9.6 MB
  float* ws        = (float*)d_ws;
  float* Akb       = ws;
  float* Avb       = Akb + (size_t)ROWS_*D_;
  float* Ckb       = Avb + (size_t)ROWS_*D_;
  float* Cvb       = Ckb + (size_t)ROWS_*D_;
  float* inv_std   = Cvb + (size_t)ROWS_*D_;            // B*N*NC*N
  float* qbuf      = inv_std + (size_t)B_*N_*NC_*N_;    // B*N*D
  float* ekv       = qbuf + B_*N_*D_;                   // 2*D
  float* part_ms   = ekv + 2*D_;                        // B*N*NC*16
  float* part_pacc = part_ms + (size_t)B_*N_*NC_*16;    // B*N*NC*D

  k_mid <<<1101, 512, 0, stream>>>(x, coords, Wp, bp, g1, b1, Wq, bq, Wk, bk, Wv, bv,
                                   Akb, Avb, Ckb, Cvb, inv_std, qbuf, ekv);
  k_attp<<<B_*N_*NC_, 256, 0, stream>>>(Akb, Avb, Ckb, Cvb, inv_std, qbuf, ekv,
                                        mask, part_ms, part_pacc);
  k_tail<<<B_*N_, 512, 0, stream>>>(part_ms, part_pacc, ekv, x, bp, Wo, bo,
                                    g2, b2, W1, bf1, W2, bfb2, (float*)d_out);
}

// Round 4
// 122.385 us; speedup vs baseline: 2.0189x; 1.2475x over previous
//
#include <hip/hip_runtime.h>

// AtomEncoderLayer: B=4, N=32, D=128, H=8, NC=27, DK=16, DFF=512, L=864.
// fp32 tensors, int32 mask.
// Low-rank collapse: phat(b,c,n) = coords(b,c,n)·Wphat (rank-3 subspace),
// dc = coords(c,n) - coords(c,i) (relative position). Exact algebra:
//   a_row centered = xh(n) + dc·Wphat,  var = var_x + (dc^T M dc + 2 dc·dxp)/D
//   K - center = is*(Axk(n) + dc·Gk) + ek,   V analog with Axv/Gv/ev
//   att_d = (Σ_n Tn[h][n] Axv[n][d] + Σ_j RD[h][j] Gv[j][d]) / S_h + ev_d
// Two kernels: k_pre (tiny per-row prep + consts), k_attn (scores + exact
// softmax + fused Wo + LN + FFN tail), one block per (b,i).

#define B_ 4
#define N_ 32
#define D_ 128
#define H_ 8
#define NC_ 27
#define DFF_ 512
#define L_ (NC_*N_)        // 864

// dual block-wide sum, blockDim = 128 (2 waves); result broadcast to all lanes
__device__ __forceinline__ void red2_block128(float& a, float& b, float* sbuf, int tid){
  for (int off = 32; off; off >>= 1){ a += __shfl_xor(a, off); b += __shfl_xor(b, off); }
  if ((tid & 63) == 0){ sbuf[(tid>>6)*2+0] = a; sbuf[(tid>>6)*2+1] = b; }
  __syncthreads();
  a = sbuf[0] + sbuf[2];
  b = sbuf[1] + sbuf[3];
  __syncthreads();   // safe reuse of sbuf
}

// dual block-wide sum, blockDim = 512 (8 waves), double-buffered by phase
__device__ __forceinline__ void bred2(float& a, float& b, float sred[2][8][2],
                                      int tid, int phase){
  for (int off = 32; off; off >>= 1){ a += __shfl_xor(a, off); b += __shfl_xor(b, off); }
  int pb = phase & 1;
  if ((tid & 63) == 0){ sred[pb][tid>>6][0] = a; sred[pb][tid>>6][1] = b; }
  __syncthreads();
  float sa = 0.f, sb = 0.f;
  #pragma unroll
  for (int w = 0; w < 8; w++){ sa += sred[pb][w][0]; sb += sred[pb][w][1]; }
  a = sa; b = sb;
}

// K1: blocks 0..127: per (b,n) row -> xh-derived quantities + Axk/Axv/q.
//     block 128: constants Gk/Gv/ek/ev/M6.
__global__ __launch_bounds__(128) void k_pre(
    const float* __restrict__ x, const float* __restrict__ Wp,
    const float* __restrict__ bp, const float* __restrict__ g1,
    const float* __restrict__ b1,
    const float* __restrict__ Wq, const float* __restrict__ bq,
    const float* __restrict__ Wk, const float* __restrict__ bk,
    const float* __restrict__ Wv, const float* __restrict__ bv,
    float* __restrict__ varx, float* __restrict__ dxp,
    float* __restrict__ Axk, float* __restrict__ Axv,
    float* __restrict__ qbuf,
    float* __restrict__ Gk, float* __restrict__ Gv,
    float* __restrict__ ekv, float* __restrict__ M6){
  __shared__ float sbuf[4];
  __shared__ float s1_[D_], s2_[D_], s3_[D_], s4_[D_];
  int blk = blockIdx.x, tid = threadIdx.x;
  float wp0 = Wp[tid], wp1 = Wp[D_+tid], wp2 = Wp[2*D_+tid];
  if (blk < 128){
    // ---- row path: r = b*32+n ----
    float t = x[blk*D_+tid] + bp[tid];
    float a = wp0, b = wp1;
    red2_block128(a, b, sbuf, tid);
    float m0 = a*(1.f/D_), m1 = b*(1.f/D_);
    float a2 = wp2, st = t;
    red2_block128(a2, st, sbuf, tid);
    float m2 = a2*(1.f/D_), mean = st*(1.f/D_);
    float xh = t - mean;
    float w0 = wp0-m0, w1 = wp1-m1, w2 = wp2-m2;
    float vv = xh*xh, d0 = xh*w0;
    red2_block128(vv, d0, sbuf, tid);
    float vx = vv*(1.f/D_);
    float d1 = xh*w1, d2 = xh*w2;
    red2_block128(d1, d2, sbuf, tid);
    s1_[tid] = xh*g1[tid];                                  // (xh*g1)
    s2_[tid] = xh*rsqrtf(vx+1e-5f)*g1[tid] + b1[tid];       // LN(x+bp) row
    __syncthreads();
    float axk = 0.f, axv = 0.f, qa = bq[tid];
    #pragma unroll 8
    for (int e=0;e<D_;e++){
      float u = s1_[e], h = s2_[e];
      axk += u*Wk[e*D_+tid];
      axv += u*Wv[e*D_+tid];
      qa  += h*Wq[e*D_+tid];
    }
    Axk[blk*D_+tid] = axk;
    Axv[blk*D_+tid] = axv;
    qbuf[blk*D_+tid] = qa;
    if (tid == 0){
      varx[blk] = vx;
      dxp[blk*3+0] = d0; dxp[blk*3+1] = d1; dxp[blk*3+2] = d2;
    }
  } else {
    // ---- consts path ----
    float a = wp0, b = wp1;
    red2_block128(a, b, sbuf, tid);
    float m0 = a*(1.f/D_), m1 = b*(1.f/D_);
    float a2 = wp2, dm = 0.f;
    red2_block128(a2, dm, sbuf, tid);
    float m2 = a2*(1.f/D_);
    float w0 = wp0-m0, w1 = wp1-m1, w2 = wp2-m2;
    float p0 = w0*w0, p1 = w0*w1;
    red2_block128(p0, p1, sbuf, tid);   // M00, M01
    float p2 = w0*w2, p3 = w1*w1;
    red2_block128(p2, p3, sbuf, tid);   // M02, M11
    float p4 = w1*w2, p5 = w2*w2;
    red2_block128(p4, p5, sbuf, tid);   // M12, M22
    float g = g1[tid];
    s1_[tid] = w0*g; s2_[tid] = w1*g; s3_[tid] = w2*g; s4_[tid] = b1[tid];
    __syncthreads();
    float gk0=0.f,gk1=0.f,gk2=0.f, gv0=0.f,gv1=0.f,gv2=0.f;
    float ek = bk[tid], ev = bv[tid];
    #pragma unroll 4
    for (int e=0;e<D_;e++){
      float wk = Wk[e*D_+tid], wv = Wv[e*D_+tid];
      gk0 += s1_[e]*wk; gk1 += s2_[e]*wk; gk2 += s3_[e]*wk;
      gv0 += s1_[e]*wv; gv1 += s2_[e]*wv; gv2 += s3_[e]*wv;
      ek  += s4_[e]*wk; ev  += s4_[e]*wv;
    }
    Gk[tid] = gk0; Gk[D_+tid] = gk1; Gk[2*D_+tid] = gk2;
    Gv[tid] = gv0; Gv[D_+tid] = gv1; Gv[2*D_+tid] = gv2;
    ekv[tid] = ek; ekv[D_+tid] = ev;
    if (tid == 0){ M6[0]=p0; M6[1]=p1; M6[2]=p2; M6[3]=p3; M6[4]=p4; M6[5]=p5; }
  }
}

// K2: one block per (b,i), 512 threads. Scores in LDS, exact 2-pass softmax
// (one wave per head), rank-3 V reconstruction, fused Wo + LN + FFN tail.
__global__ __launch_bounds__(512) void k_attn(
    const float* __restrict__ coords, const int* __restrict__ mask,
    const float* __restrict__ x, const float* __restrict__ bp,
    const float* __restrict__ varx, const float* __restrict__ dxp,
    const float* __restrict__ Axk, const float* __restrict__ Axv,
    const float* __restrict__ qbuf,
    const float* __restrict__ Gk, const float* __restrict__ Gv,
    const float* __restrict__ ekv, const float* __restrict__ M6,
    const float* __restrict__ Wo, const float* __restrict__ bo,
    const float* __restrict__ g2, const float* __restrict__ b2,
    const float* __restrict__ W1, const float* __restrict__ bf1,
    const float* __restrict__ W2, const float* __restrict__ bfb2,
    float* __restrict__ out){
  __shared__ float sc_s[H_*L_];      // 27648 B
  __shared__ float is_s[L_];
  __shared__ float cq_s[NC_][3];
  __shared__ float q_s[D_];
  __shared__ float qAxk_s[H_][N_];
  __shared__ float qGk_s[H_][3];
  __shared__ float S3_s[H_];
  __shared__ float varx_s[N_];
  __shared__ float dxp_s[N_][3];
  __shared__ int   mask_s[N_];
  __shared__ float Tnp_s[H_][2][N_];
  __shared__ float Sh_s[H_], RD_s[H_][3];
  __shared__ float M6_s[6];
  __shared__ float att_s[D_], y_s[D_], hn_s[D_], f_s[DFF_];
  __shared__ float po[4][D_];
  __shared__ float sred[2][8][2];
  int bi = blockIdx.x;               // b*32+i
  int b = bi >> 5, i = bi & 31;
  int tid = threadIdx.x;

  // ---- stage small per-(b,i) data ----
  if (tid < D_) q_s[tid] = qbuf[bi*D_+tid];
  if (tid < N_){ varx_s[tid] = varx[b*N_+tid]; mask_s[tid] = mask[b*N_+tid]; }
  if (tid >= 32 && tid < 128){
    int t2 = tid - 32;                       // 96 = 32 rows x 3
    dxp_s[t2/3][t2%3] = dxp[(b*N_ + t2/3)*3 + t2%3];
  }
  if (tid >= 128 && tid < 128+NC_*3){
    int t2 = tid - 128;                      // 81 = 27 images x 3 (query coords)
    cq_s[t2/3][t2%3] = coords[((size_t)(b*NC_ + t2/3)*N_ + i)*3 + t2%3];
  }
  if (tid >= 256 && tid < 262) M6_s[tid-256] = M6[tid-256];
  __syncthreads();

  // ---- q-derived constants ----
  if (tid < 256){
    int h = tid >> 5, n = tid & 31;
    float s = 0.f;
    #pragma unroll
    for (int k=0;k<16;k++) s += q_s[h*16+k]*Axk[(size_t)(b*N_+n)*D_ + h*16+k];
    qAxk_s[h][n] = s;
  } else if (tid < 256+24){
    int t2 = tid-256, h = t2/3, j = t2%3;
    float s = 0.f;
    #pragma unroll
    for (int k=0;k<16;k++) s += q_s[h*16+k]*Gk[j*D_ + h*16+k];
    qGk_s[h][j] = s;
  } else if (tid < 280+8){
    int h = tid-280;
    float s = 0.f;
    #pragma unroll
    for (int k=0;k<16;k++) s += q_s[h*16+k]*ekv[h*16+k];
    S3_s[h] = s;
  }
  __syncthreads();

  // ---- pass 1: inv_std + 8 head scores per key l=(c,n) ----
  for (int l = tid; l < L_; l += 512){
    int c = l >> 5, n = l & 31;
    const float* ck = coords + ((size_t)(b*NC_+c)*N_ + n)*3;
    float d0 = ck[0]-cq_s[c][0], d1 = ck[1]-cq_s[c][1], d2 = ck[2]-cq_s[c][2];
    float quad = d0*d0*M6_s[0] + d1*d1*M6_s[3] + d2*d2*M6_s[5]
               + 2.f*(d0*d1*M6_s[1] + d0*d2*M6_s[2] + d1*d2*M6_s[4]);
    float lin  = d0*dxp_s[n][0] + d1*dxp_s[n][1] + d2*dxp_s[n][2];
    float E = varx_s[n] + (quad + 2.f*lin)*(1.f/D_);
    float is = rsqrtf(fmaxf(E, 0.f) + 1e-5f);
    is_s[l] = is;
    bool mk = mask_s[n] != 0;
    #pragma unroll
    for (int h=0; h<H_; h++){
      float sc = 0.25f*(is*(qAxk_s[h][n]
                 + d0*qGk_s[h][0] + d1*qGk_s[h][1] + d2*qGk_s[h][2]) + S3_s[h]);
      sc_s[h*L_ + l] = mk ? sc : -1e9f;
    }
  }
  __syncthreads();

  // ---- pass 2: exact softmax, one wave per head ----
  {
    int h = tid >> 6, lane = tid & 63, n = lane & 31, half = lane >> 5;
    int c0 = half ? 14 : 0, c1 = half ? NC_ : 14;
    float M = -3.0e38f;
    for (int c=c0; c<c1; c++) M = fmaxf(M, sc_s[h*L_ + c*N_ + n]);
    for (int off=32; off; off>>=1) M = fmaxf(M, __shfl_xor(M, off));
    float S=0.f, Tn=0.f, r0=0.f, r1=0.f, r2=0.f;
    for (int c=c0; c<c1; c++){
      int l = c*N_ + n;
      float w = expf(sc_s[h*L_ + l] - M);
      float t = w * is_s[l];
      S += w; Tn += t;
      const float* ck = coords + ((size_t)(b*NC_+c)*N_ + n)*3;
      r0 += t*(ck[0]-cq_s[c][0]);
      r1 += t*(ck[1]-cq_s[c][1]);
      r2 += t*(ck[2]-cq_s[c][2]);
    }
    Tnp_s[h][half][n] = Tn;
    for (int off=32; off; off>>=1){
      S  += __shfl_xor(S,  off);
      r0 += __shfl_xor(r0, off);
      r1 += __shfl_xor(r1, off);
      r2 += __shfl_xor(r2, off);
    }
    if (lane == 0){ Sh_s[h]=S; RD_s[h][0]=r0; RD_s[h][1]=r1; RD_s[h][2]=r2; }
  }
  __syncthreads();

  // ---- attention output: rank-3 V reconstruction ----
  {
    int slot = tid >> 7, d = tid & 127, h = d >> 4;
    float pa = 0.f;
    #pragma unroll
    for (int n = slot*8; n < slot*8+8; n++){
      float Tn = Tnp_s[h][0][n] + Tnp_s[h][1][n];
      pa += Tn * Axv[(size_t)(b*N_+n)*D_ + d];
    }
    if (slot == 0)
      pa += RD_s[h][0]*Gv[d] + RD_s[h][1]*Gv[D_+d] + RD_s[h][2]*Gv[2*D_+d];
    po[slot][d] = pa;
  }
  __syncthreads();
  if (tid < D_){
    int h = tid >> 4;
    att_s[tid] = (po[0][tid]+po[1][tid]+po[2][tid]+po[3][tid])
                 / fmaxf(Sh_s[h], 1e-30f) + ekv[D_+tid];
  }
  __syncthreads();

  // ---- Wo + residual ----
  {
    int slot = tid >> 7, d = tid & 127;
    float a = 0.f;
    #pragma unroll 8
    for (int e=slot*32; e<slot*32+32; e++) a += att_s[e]*Wo[e*D_+d];
    po[slot][d] = a;
  }
  __syncthreads();
  float yv = 0.f;
  if (tid < D_){
    yv = x[bi*D_+tid] + bp[tid] + bo[tid]
       + po[0][tid]+po[1][tid]+po[2][tid]+po[3][tid];
    y_s[tid] = yv;
  }
  // ---- LN2 ----
  float s1 = (tid < D_) ? yv : 0.f, dm = 0.f;
  bred2(s1, dm, sred, tid, 0);
  float dev = yv - s1*(1.f/D_);
  float v1 = (tid < D_) ? dev*dev : 0.f; dm = 0.f;
  bred2(v1, dm, sred, tid, 1);
  if (tid < D_) hn_s[tid] = dev*rsqrtf(v1*(1.f/D_)+1e-5f)*g2[tid] + b2[tid];
  __syncthreads();
  // ---- FFN ----
  float f = bf1[tid];
  #pragma unroll 8
  for (int e=0;e<D_;e++) f += hn_s[e]*W1[e*DFF_+tid];
  f_s[tid] = fmaxf(f, 0.f);
  __syncthreads();
  {
    int slot = tid >> 7, d = tid & 127;
    float a = 0.f;
    #pragma unroll 8
    for (int j=slot*128; j<slot*128+128; j++) a += f_s[j]*W2[j*D_+d];
    po[slot][d] = a;
  }
  __syncthreads();
  if (tid < D_)
    out[bi*D_+tid] = y_s[tid] + bfb2[tid]
                   + po[0][tid]+po[1][tid]+po[2][tid]+po[3][tid];
}

extern "C" void kernel_launch(void* const* d_in, const int* in_sizes, int n_in,
                              void* d_out, int out_size, void* d_ws, size_t ws_size,
                              hipStream_t stream){
  const float* x      = (const float*)d_in[0];
  const int*   mask   = (const int*)  d_in[1];
  const float* coords = (const float*)d_in[2];
  const float* Wp     = (const float*)d_in[3];
  const float* bp     = (const float*)d_in[4];
  const float* Wq     = (const float*)d_in[5];
  const float* bq     = (const float*)d_in[6];
  const float* Wk     = (const float*)d_in[7];
  const float* bk     = (const float*)d_in[8];
  const float* Wv     = (const float*)d_in[9];
  const float* bv     = (const float*)d_in[10];
  const float* Wo     = (const float*)d_in[11];
  const float* bo     = (const float*)d_in[12];
  const float* g1     = (const float*)d_in[13];
  const float* b1     = (const float*)d_in[14];
  const float* g2     = (const float*)d_in[15];
  const float* b2     = (const float*)d_in[16];
  const float* W1     = (const float*)d_in[17];
  const float* bf1    = (const float*)d_in[18];
  const float* W2     = (const float*)d_in[19];
  const float* bfb2   = (const float*)d_in[20];

  // ws layout (fp32), ~200 KB total
  float* ws   = (float*)d_ws;
  float* varx = ws;                  // 128
  float* dxp  = varx + 128;          // 384
  float* M6   = dxp  + 384;          // 8
  float* Gk   = M6   + 8;            // 384
  float* Gv   = Gk   + 384;          // 384
  float* ekv  = Gv   + 384;          // 256
  float* Axk  = ekv  + 256;          // 16384
  float* Axv  = Axk  + 16384;        // 16384
  float* qbuf = Axv  + 16384;        // 16384

  k_pre <<<129, 128, 0, stream>>>(x, Wp, bp, g1, b1, Wq, bq, Wk, bk, Wv, bv,
                                  varx, dxp, Axk, Axv, qbuf, Gk, Gv, ekv, M6);
  k_attn<<<B_*N_, 512, 0, stream>>>(coords, mask, x, bp, varx, dxp, Axk, Axv,
                                    qbuf, Gk, Gv, ekv, M6, Wo, bo, g2, b2,
                                    W1, bf1, W2, bfb2, (float*)d_out);
}